// Round 12
// baseline (114.122 us; speedup 1.0000x reference)
//
#include <hip/hip_runtime.h>

#define NQ 8
#define BINS 256
#define D 128
#define RPB 32            // rows per block
#define THREADS 1024      // 16 waves; grid = 256 -> 1 block/CU -> 4 waves/SIMD
#define RSTRIDE 132       // prep staging stride
#define FREG 520          // shorts per frag region (512 + 8 pad)

typedef short s8v __attribute__((ext_vector_type(8)));   // 8 bf16 in 4 VGPRs
typedef short s4v __attribute__((ext_vector_type(4)));   // 4 bf16 in 2 VGPRs
typedef float f4v __attribute__((ext_vector_type(4)));   // MFMA accumulator

static __device__ __forceinline__ unsigned short bf16_rtne(float x) {
    unsigned u = __float_as_uint(x);
    unsigned r = (u + 0x7fffu + ((u >> 16) & 1u)) >> 16;
    return (unsigned short)r;
}
static __device__ __forceinline__ float bf16_to_f(unsigned short h) {
    return __uint_as_float(((unsigned)h) << 16);
}
struct Split3 { short h, m, l; };
static __device__ __forceinline__ Split3 split3(float x) {
    Split3 s;
    unsigned short hb = bf16_rtne(x);
    float r1 = x - bf16_to_f(hb);
    unsigned short mb = bf16_rtne(r1);
    unsigned short lb = bf16_rtne(r1 - bf16_to_f(mb));
    s.h = (short)hb; s.m = (short)mb; s.l = (short)lb;
    return s;
}
static __device__ __forceinline__ unsigned long long shfl_xor_u64(unsigned long long v, int mask) {
    int lo = (int)(unsigned)(v & 0xffffffffull);
    int hi = (int)(unsigned)(v >> 32);
    lo = __shfl_xor(lo, mask, 64);
    hi = __shfl_xor(hi, mask, 64);
    return ((unsigned long long)(unsigned)hi << 32) | (unsigned)lo;
}
static __device__ __forceinline__ unsigned long long u64min(unsigned long long a, unsigned long long b) {
    return a < b ? a : b;
}

// ---- prep: identical to R7/R11 (passed) ----
__global__ __launch_bounds__(256) void rvq_prep(
    const float* __restrict__ cb, short* __restrict__ cb_hi,
    short* __restrict__ cb_mid, short* __restrict__ cb_lo,
    float* __restrict__ c2)
{
    __shared__ float st[16 * RSTRIDE];
    const int L = blockIdx.x >> 4;
    const int o = blockIdx.x & 15;
    const int t = threadIdx.x;

    const float4* src = (const float4*)(cb + ((size_t)L * BINS + o * 16) * D);
    #pragma unroll
    for (int i = 0; i < 2; ++i) {
        int f4 = i * 256 + t;
        int row = f4 >> 5, c4 = f4 & 31;
        float4 v = src[f4];
        float* d = &st[row * RSTRIDE + c4 * 4];
        d[0] = v.x; d[1] = v.y; d[2] = v.z; d[3] = v.w;
    }
    __syncthreads();

    const int bin = t >> 4;
    const int kc  = t & 15;
    const float* p = &st[bin * RSTRIDE + kc * 8];
    s8v h8, m8, l8;
    float s = 0.f;
    #pragma unroll
    for (int j = 0; j < 8; ++j) {
        float x = p[j];
        Split3 sp = split3(x);
        h8[j] = sp.h; m8[j] = sp.m; l8[j] = sp.l;
        s = fmaf(x, x, s);
    }
    int idx = (L * 16 + kc) * BINS + (o * 16 + bin);
    ((s8v*)cb_hi)[idx]  = h8;
    ((s8v*)cb_mid)[idx] = m8;
    ((s8v*)cb_lo)[idx]  = l8;
    s += __shfl_xor(s, 1, 64);
    s += __shfl_xor(s, 2, 64);
    s += __shfl_xor(s, 4, 64);
    s += __shfl_xor(s, 8, 64);
    if (kc == 0) c2[L * BINS + o * 16 + bin] = s;
}

// frag store, 4-element half-slot (R11's, passed)
static __device__ __forceinline__ void frag_store4(
    const float* rres, short* ah, short* am, short* al, int rr_, int g8, int half)
{
    s4v h4, m4, l4;
    #pragma unroll
    for (int j = 0; j < 4; ++j) {
        Split3 sp = split3(rres[j]);
        h4[j] = sp.h; m4[j] = sp.m; l4[j] = sp.l;
    }
    int q = g8 & 3;
    int reg = (rr_ >> 4) * 4 + (g8 >> 2);          // mt*4 + ks
    int idx16 = q * 16 + (((rr_ & 15) + 4 * q) & 15);
    int off = reg * FREG + idx16 * 8 + half * 4;
    *(s4v*)&ah[off] = h4;
    *(s4v*)&am[off] = m4;
    *(s4v*)&al[off] = l4;
}

// one mt half: load A from LDS, 3-chain MFMA, keys, 16-lane argmin, stash
static __device__ __forceinline__ void do_mt(
    int mt, const short* ah, const short* am, const short* al,
    const s8v* bh, const s8v* bm, const s8v* bl,
    float c2v, int bin, int idx16, int quad, int m, int w,
    unsigned long long (*redw)[16])
{
    s8v afh[4], afm[4], afl[4];
    #pragma unroll
    for (int ks = 0; ks < 4; ++ks) {
        int off = (mt * 4 + ks) * FREG + idx16 * 8;
        afh[ks] = *(const s8v*)&ah[off];
        afm[ks] = *(const s8v*)&am[off];
        afl[ks] = *(const s8v*)&al[off];
    }
    f4v a0 = {0.f, 0.f, 0.f, 0.f};   // hh
    f4v a1 = {0.f, 0.f, 0.f, 0.f};   // hm + mh
    f4v a2 = {0.f, 0.f, 0.f, 0.f};   // mm + hl + lh
    #pragma unroll
    for (int ks = 0; ks < 4; ++ks) {
        a0 = __builtin_amdgcn_mfma_f32_16x16x32_bf16(afh[ks], bh[ks], a0, 0, 0, 0);
        a1 = __builtin_amdgcn_mfma_f32_16x16x32_bf16(afh[ks], bm[ks], a1, 0, 0, 0);
        a1 = __builtin_amdgcn_mfma_f32_16x16x32_bf16(afm[ks], bh[ks], a1, 0, 0, 0);
        a2 = __builtin_amdgcn_mfma_f32_16x16x32_bf16(afm[ks], bm[ks], a2, 0, 0, 0);
        a2 = __builtin_amdgcn_mfma_f32_16x16x32_bf16(afh[ks], bl[ks], a2, 0, 0, 0);
        a2 = __builtin_amdgcn_mfma_f32_16x16x32_bf16(afl[ks], bh[ks], a2, 0, 0, 0);
    }
    #pragma unroll
    for (int i = 0; i < 4; ++i) {
        float dot = a0[i] + (a1[i] + a2[i]);
        float k = fmaf(-2.f, dot, c2v);
        unsigned u = __float_as_uint(k);
        u = (u & 0x80000000u) ? ~u : (u | 0x80000000u);
        unsigned long long p = ((unsigned long long)u << 32) | (unsigned)bin;
        p = u64min(p, shfl_xor_u64(p, 1));
        p = u64min(p, shfl_xor_u64(p, 2));
        p = u64min(p, shfl_xor_u64(p, 4));
        p = u64min(p, shfl_xor_u64(p, 8));
        if (m == 0) redw[mt * 16 + quad * 4 + i][w] = p;
    }
}

// ---- main: 32 rows, 16 waves (4/SIMD forced); wave = one 16-bin window ----
__global__ __launch_bounds__(THREADS)
__attribute__((amdgpu_waves_per_eu(4, 4)))
void rvq_kernel(
    const float* __restrict__ hidden,     // [N, D]
    const float* __restrict__ cb_f32,     // [NQ, BINS, D]
    const short* __restrict__ cb_hi,
    const short* __restrict__ cb_mid,
    const short* __restrict__ cb_lo,
    const float* __restrict__ c2p,        // [NQ, BINS]
    float* __restrict__ out_codes,        // [NQ, N] as float
    float* __restrict__ out_quant,        // [N, D]
    int N)
{
    __shared__ short ah[8 * FREG];
    __shared__ short am[8 * FREG];
    __shared__ short al[8 * FREG];
    __shared__ unsigned long long redw[RPB][16];

    const int t = threadIdx.x;
    const int w = t >> 6;                 // wave 0..15
    const int l = t & 63;
    const int quad = l >> 4;
    const int m = l & 15;
    const int row0 = blockIdx.x * RPB;
    const int bin = w * 16 + m;           // this wave's bin
    const int rr_ = t >> 5;               // owned row 0..31
    const int g4 = t & 31;                // owned dim-quarter (4 floats)
    const int g8 = g4 >> 1;               // kchunk 0..15
    const int half = g4 & 1;

    float rres[4];
    {
        const float4* hp = (const float4*)(hidden + (size_t)(row0 + rr_) * D + g4 * 4);
        float4 v = hp[0];
        rres[0] = v.x; rres[1] = v.y; rres[2] = v.z; rres[3] = v.w;
    }
    frag_store4(rres, ah, am, al, rr_, g8, half);

    const s8v* bhp = (const s8v*)cb_hi;
    const s8v* bmp = (const s8v*)cb_mid;
    const s8v* blp = (const s8v*)cb_lo;

    // bootstrap B prefetch for level 0
    s8v bh[4], bm[4], bl[4];
    float c2v;
    {
        c2v = c2p[bin];
        #pragma unroll
        for (int ks = 0; ks < 4; ++ks) {
            int idx = (ks * 4 + quad) * BINS + bin;
            bh[ks] = bhp[idx];
            bm[ks] = bmp[idx];
            bl[ks] = blp[idx];
        }
    }

    const int idx16 = quad * 16 + ((m + 4 * quad) & 15);

    for (int level = 0; level < NQ; ++level) {
        __syncthreads();   // barrier1: A-frag writes visible

        // mt halves processed sequentially: A regs live one half at a time
        do_mt(0, ah, am, al, bh, bm, bl, c2v, bin, idx16, quad, m, w, redw);
        do_mt(1, ah, am, al, bh, bm, bl, c2v, bin, idx16, quad, m, w, redw);

        // prefetch next level's B (flies under barrier2 + update + barrier1)
        if (level + 1 < NQ) {
            c2v = c2p[(level + 1) * BINS + bin];
            #pragma unroll
            for (int ks = 0; ks < 4; ++ks) {
                int idx = ((level + 1) * 16 + ks * 4 + quad) * BINS + bin;
                bh[ks] = bhp[idx];
                bm[ks] = bmp[idx];
                bl[ks] = blp[idx];
            }
        }
        __syncthreads();   // barrier2: redw visible

        // every thread reduces its own row's 16 wave-results (broadcast reads)
        unsigned long long mn = redw[rr_][0];
        #pragma unroll
        for (int j = 1; j < 16; ++j) mn = u64min(mn, redw[rr_][j]);
        const int wb = (int)(mn & 0xffffffffull);
        if (g4 == 0)
            out_codes[(size_t)level * N + row0 + rr_] = (float)wb;

        // fp32 residual update in registers (elementwise, matches reference)
        {
            const float4* cp = (const float4*)(cb_f32 + ((size_t)level * BINS + wb) * D + g4 * 4);
            float4 c = cp[0];
            rres[0] -= c.x; rres[1] -= c.y; rres[2] -= c.z; rres[3] -= c.w;
        }
        frag_store4(rres, ah, am, al, rr_, g8, half);
    }

    // epilogue: quantized = hidden - residual
    {
        const float4* hp = (const float4*)(hidden + (size_t)(row0 + rr_) * D + g4 * 4);
        float4 v = hp[0];
        float4 q;
        q.x = v.x - rres[0]; q.y = v.y - rres[1]; q.z = v.z - rres[2]; q.w = v.w - rres[3];
        float4* op = (float4*)(out_quant + (size_t)(row0 + rr_) * D + g4 * 4);
        op[0] = q;
    }
}

extern "C" void kernel_launch(void* const* d_in, const int* in_sizes, int n_in,
                              void* d_out, int out_size, void* d_ws, size_t ws_size,
                              hipStream_t stream) {
    const float* hidden    = (const float*)d_in[0];
    const float* codebooks = (const float*)d_in[1];
    float* out = (float*)d_out;
    const int N = in_sizes[0] / D;                 // 8192
    float* out_codes = out;                        // [NQ, N]
    float* out_quant = out + (size_t)NQ * N;       // [N, D]

    char* ws = (char*)d_ws;
    short* cb_hi  = (short*)ws;                    // 512 KB
    short* cb_mid = (short*)(ws +  512 * 1024);    // 512 KB
    short* cb_lo  = (short*)(ws + 1024 * 1024);    // 512 KB
    float* c2     = (float*)(ws + 1536 * 1024);    // 8 KB

    rvq_prep<<<dim3(NQ * 16), 256, 0, stream>>>(codebooks, cb_hi, cb_mid, cb_lo, c2);
    rvq_kernel<<<dim3(N / RPB), THREADS, 0, stream>>>(
        hidden, codebooks, cb_hi, cb_mid, cb_lo, c2, out_codes, out_quant, N);
}